// Round 15
// baseline (1030.933 us; speedup 1.0000x reference)
//
#include <hip/hip_runtime.h>

// DynamicFilter: out[b,c,h,w] = sum_p (y[c*9+p] + bias[c*9+p]) * x[b,c,h+dh,w+dw]
//   y[o] = sum_c' x[b,c',h,w] * W[o,c']   (GEMM M=65536, N=2304, K=256, bf16 MFMA)
// B=4, C=256, H=W=128, 9 taps.
// R15 126us (ppw32, 8 waves/CU, all pipes <=37% -> stalled on lgkm deps at 2
//   waves/SIMD). R16 (chunk-split + (256,3)) SPILLED: VGPR 84, +300 MB
//   scratch, 230us. ppw32 live state afr64+acc72 ~ 150 regs doesn't fit 170.
// R17: shrink acc 72 -> 24(+8) by K-then-N reorder. Sub read order
//   [0,3 | 1,4 | 2,5]: after each (kh0,kh1) pair the 3-ni group is COMPLETE
//   -> partial epilogue immediately (group g owns compile-time idx slots
//   12g..12g+11 -> (c4,p)), fold into sum[2][4] carried across groups;
//   stores at chunk end. Live: afr 64 + acc[2][3] 24 + sum 8 ~ 96-125.
//   Structure: grid 1024 = 512 (b,h) x 2 chunk-halves (8 chunks each),
//   ring-4 (49152 B -> 3 blocks/CU), (256,3) -> 12 waves/CU at R15's LDS
//   traffic. Epi patch loads interleave 3x/chunk = natural vm retire points.
//   Position p (read sub S=[0,3,1,4,2,5][p], buf (lc*6+p)&3) stages the
//   sub of position p+3 into buf (lc*6+p+3)&3 = previous position's read
//   buf (WAR drained by this SYNC's lgkm+barrier). Waits: p0 VM(8) [stores
//   only], p1 VM(11) [+p0 stage], p2 VM(6) [all older retired by epi0],
//   p3 VM(3) [keep p2 stage], p4/p5 VM(6). FENCE pins stages before epis.

typedef __attribute__((ext_vector_type(8))) short bf16x8;   // 8 bf16 = 4 VGPRs
typedef __attribute__((ext_vector_type(4))) float f32x4;    // MFMA 16x16 acc

__device__ __forceinline__ unsigned int f2bf(float f) {
    unsigned int u = __float_as_uint(f);
    return (u + 0x7fffu + ((u >> 16) & 1u)) >> 16;   // RNE
}
__device__ __forceinline__ unsigned int pack2(float a, float b) {
    return f2bf(a) | (f2bf(b) << 16);
}

// ---------------------------------------------------------------------------
// Kernel 1: W (2304x256 fp32) -> Wb bf16, instruction-ordered A-fragments
// with channel-aligned out permutation (unchanged from R11..R16):
//   o: chunk=o/144, oc=o%144, c_local=oc/9, p=oc%9
//   q=c_local/4, c4=c_local%4, idx=c4*9+p, ni=idx/4, j=idx%4, r=q*4+j
//   k: kh=k/128, s=(k%128)/32, kq=(k%32)/8, e=k%8; jsub=kh*3+ni/3; ni_=ni%3
//   dst = chunk*73728 + jsub*12288 + (s*3+ni_)*1024 + (kq*16+r)*16 + e*2
// ---------------------------------------------------------------------------
__global__ __launch_bounds__(256) void wconv_kernel(const float* __restrict__ W,
                                                    unsigned char* __restrict__ Wb) {
    int idx0 = blockIdx.x * 256 + threadIdx.x;   // 73728 = 2304 * 32 groups
    int o = idx0 >> 5, g = idx0 & 31;
    const float4* src = (const float4*)(W + ((size_t)o << 8) + ((size_t)g << 3));
    float4 v0 = src[0], v1 = src[1];
    uint4 pk;
    pk.x = pack2(v0.x, v0.y); pk.y = pack2(v0.z, v0.w);
    pk.z = pack2(v1.x, v1.y); pk.w = pack2(v1.z, v1.w);
    int kh = g >> 4, g2 = g & 15, s = g2 >> 2, kq = g2 & 3;
    int chunk = o / 144, oc = o - chunk * 144;
    int c_local = oc / 9, p = oc - c_local * 9;
    int q = c_local >> 2, c4 = c_local & 3;
    int idx = c4 * 9 + p;
    int ni = idx >> 2, j = idx & 3, r = (q << 2) + j;
    int jsub = kh * 3 + ni / 3, ni_ = ni % 3;
    size_t dst = (size_t)chunk * 73728 + (size_t)jsub * 12288
               + (size_t)(s * 3 + ni_) * 1024 + (size_t)((kq << 4) + r) * 16;
    *(uint4*)(Wb + dst) = pk;
}

// ---------------------------------------------------------------------------
// Kernel 2. LDS: ring-4 bufs at buf*12288, 49152 B total -> 3 blocks/CU.
// ---------------------------------------------------------------------------

#define SYNC_VM(N) asm volatile("s_waitcnt vmcnt(" #N ") lgkmcnt(0)\n\ts_barrier" ::: "memory")
#define FENCE      asm volatile("" ::: "memory")   // compile-time order pin only

// Stage sub-tile J (0..5) of chunk CH into ring buf BUF. Wave wv stages
// 3072 B as 3 x global_load_lds(16B). Per-wave vmcnt += 3.
#define STAGE(CH, J, BUF)                                                       \
    do {                                                                        \
        const unsigned char* bs_ = Wb + (size_t)(CH) * 73728                    \
            + (size_t)(J) * 12288 + wv * 3072 + (lane << 4);                    \
        unsigned char* bd_ = smem + (size_t)(BUF) * 12288 + wv * 3072;          \
        _Pragma("unroll")                                                       \
        for (int c_ = 0; c_ < 3; ++c_)                                          \
            __builtin_amdgcn_global_load_lds(                                   \
                (const __attribute__((address_space(1))) void*)(bs_ + c_ * 1024), \
                (__attribute__((address_space(3))) void*)(bd_ + c_ * 1024), 16, 0, 0); \
    } while (0)

// One kh half of a 3-ni group: 12 MFMAs (3 l x 4 s x ... x 2 mi = 24) sharing
// 12 ds_read_b128. acc[mi][l] (l = local ni). A = Wb frag (uniform base +
// lane*16, conflict-free), B = afr.
#define MFMA_HALF(KH, BUF)                                                      \
    do {                                                                        \
        const unsigned char* bb_ = smem + (size_t)(BUF) * 12288 + (lane << 4);  \
        _Pragma("unroll")                                                       \
        for (int s_ = 0; s_ < 4; ++s_) {                                        \
            const bf16x8 a0_ = afr[((KH) << 2) + s_];                           \
            const bf16x8 a1_ = afr[8 + ((KH) << 2) + s_];                       \
            _Pragma("unroll")                                                   \
            for (int l_ = 0; l_ < 3; ++l_) {                                    \
                const bf16x8 bq_ = *(const bf16x8*)(bb_ + ((s_ * 3 + l_) << 10)); \
                acc[0][l_] = __builtin_amdgcn_mfma_f32_16x16x32_bf16(           \
                    bq_, a0_, acc[0][l_], 0, 0, 0);                             \
                acc[1][l_] = __builtin_amdgcn_mfma_f32_16x16x32_bf16(           \
                    bq_, a1_, acc[1][l_], 0, 0, 0);                             \
            }                                                                   \
        }                                                                       \
    } while (0)

// Partial epilogue for group G (idx 12G..12G+11, all indices compile-time):
// sum[mi][c4] += (acc[mi][l][j] + bias)*patch. acc then reusable.
#define EPI_G(G)                                                                \
    do {                                                                        \
        _Pragma("unroll")                                                       \
        for (int mi_ = 0; mi_ < 2; ++mi_) {                                     \
            const int w_ = (wv << 5) + (mi_ << 4) + lrow;                       \
            _Pragma("unroll")                                                   \
            for (int ii_ = 0; ii_ < 12; ++ii_) {                                \
                const int idx_ = 12 * (G) + ii_;                                \
                const int c4_ = idx_ / 9, p_ = idx_ - 9 * c4_;                  \
                const int l_ = ii_ >> 2, j_ = ii_ & 3;                          \
                const int cg_ = (chunk << 4) + (quad << 2) + c4_;               \
                const int hh_ = h + p_ / 3 - 1, ww_ = w_ + p_ % 3 - 1;          \
                float xv_ = 0.f;                                                \
                if ((unsigned)hh_ < 128u && (unsigned)ww_ < 128u)               \
                    xv_ = x[((size_t)((b << 8) + cg_) << 14) + (hh_ << 7) + ww_]; \
                sum[mi_][c4_] += (acc[mi_][l_][j_] + bias[cg_ * 9 + p_]) * xv_; \
            }                                                                   \
        }                                                                       \
    } while (0)

#define ZERO_ACC                                                                \
    do {                                                                        \
        const f32x4 z_ = {0.f, 0.f, 0.f, 0.f};                                  \
        _Pragma("unroll")                                                       \
        for (int mi_ = 0; mi_ < 2; ++mi_)                                       \
            _Pragma("unroll")                                                   \
            for (int l_ = 0; l_ < 3; ++l_) acc[mi_][l_] = z_;                   \
    } while (0)

__global__ __launch_bounds__(256, 3) void dfgemm_kernel(
        const unsigned char* __restrict__ Wb, const float* __restrict__ x,
        const float* __restrict__ bias, float* __restrict__ out) {
    __shared__ __align__(16) unsigned char smem[49152];

    const int t = threadIdx.x;
    const int lane = t & 63, wv = t >> 6;        // wv 0..3
    const int quad = lane >> 4, lrow = lane & 15;

    const int half = blockIdx.x & 1;             // chunk half (adjacent bids
    const int rowid = blockIdx.x >> 1;           //  share a row -> L2 reuse)
    const int b = rowid >> 7;                    // image 0..3
    const int h = rowid & 127;                   // row
    const int c0 = half << 3;                    // first chunk of this half

    // Prologue: stage read-positions 0,1,2 of chunk c0 = subs 0,3,1 -> bufs 0,1,2.
    STAGE(c0, 0, 0); STAGE(c0, 3, 1); STAGE(c0, 1, 2);

    // ---- A(pixel) fragments: afr[mi*8+kh*4+s][e] = bf16(x[b, ch, h, w]) ----
    bf16x8 afr[16];
    {
        const float* xrow = x + ((size_t)b << 22) + (h << 7);
        #pragma unroll
        for (int mi = 0; mi < 2; ++mi) {
            const int w = (wv << 5) + (mi << 4) + lrow;
            #pragma unroll
            for (int gg = 0; gg < 8; ++gg) {
                const float* p = xrow + ((size_t)((gg << 5) + (quad << 3)) << 14) + w;
                float v[8];
                #pragma unroll
                for (int e = 0; e < 8; ++e) v[e] = p[(size_t)e << 14];
                uint4 pk;
                pk.x = pack2(v[0], v[1]); pk.y = pack2(v[2], v[3]);
                pk.z = pack2(v[4], v[5]); pk.w = pack2(v[6], v[7]);
                afr[(mi << 3) + gg] = *(const bf16x8*)&pk;
            }
        }
    }
    SYNC_VM(0);                        // prologue only: full drain

    #pragma unroll 1
    for (int lc = 0; lc < 8; ++lc) {
        const int chunk = c0 + lc;
        const int cnext = c0 + ((lc + 1) & 7);   // tail wraps: harmless re-stage
        const int bb0 = (lc * 6) & 3;            // buf of this chunk's position 0
        f32x4 acc[2][3];
        float sum[2][4];
        #pragma unroll
        for (int mi = 0; mi < 2; ++mi)
            #pragma unroll
            for (int c4 = 0; c4 < 4; ++c4) sum[mi][c4] = 0.f;

        // ---- group 0: subs 0 (kh0) + 3 (kh1), then partial epilogue ----
        ZERO_ACC;
        SYNC_VM(8);                            // p0: stores only outstanding
        STAGE(chunk, 4, (bb0 + 3) & 3);        // for p3
        MFMA_HALF(0, bb0);                     // sub0

        SYNC_VM(11);                           // p1: stores + p0 stage
        STAGE(chunk, 2, (bb0 + 0) & 3);        // for p4 (buf (bb0+4)&3 = bb0)
        MFMA_HALF(1, (bb0 + 1) & 3);           // sub3
        FENCE;
        EPI_G(0);

        // ---- group 1: subs 1 (kh0) + 4 (kh1) ----
        ZERO_ACC;
        SYNC_VM(6);                            // p2: older all retired by epi0
        STAGE(chunk, 5, (bb0 + 1) & 3);        // for p5
        MFMA_HALF(0, (bb0 + 2) & 3);           // sub1

        SYNC_VM(3);                            // p3: keep p2 stage in flight
        STAGE(cnext, 0, (bb0 + 2) & 3);        // for next p0
        MFMA_HALF(1, (bb0 + 3) & 3);           // sub4
        FENCE;
        EPI_G(1);

        // ---- group 2: subs 2 (kh0) + 5 (kh1) ----
        ZERO_ACC;
        SYNC_VM(6);                            // p4: p2 retired by epi1; p3 flies
        STAGE(cnext, 3, (bb0 + 3) & 3);        // for next p1
        MFMA_HALF(0, bb0);                     // sub2 (staged p1 -> buf bb0)

        SYNC_VM(6);                            // p5: p3 retired by epi1; p4 flies
        STAGE(cnext, 1, (bb0 + 0) & 3);        // for next p2 (buf (bb0+6)&3)
        MFMA_HALF(1, (bb0 + 1) & 3);           // sub5 (staged p2 -> buf (bb0+5)&3)
        FENCE;
        EPI_G(2);

        // ---- stores: lane's 2 pixels x 4 channels ----
        #pragma unroll
        for (int mi = 0; mi < 2; ++mi) {
            const int w = (wv << 5) + (mi << 4) + lrow;
            #pragma unroll
            for (int c4 = 0; c4 < 4; ++c4) {
                const int cg = (chunk << 4) + (quad << 2) + c4;
                out[((size_t)((b << 8) + cg) << 14) + (h << 7) + w] = sum[mi][c4];
            }
        }
    }
}

extern "C" void kernel_launch(void* const* d_in, const int* in_sizes, int n_in,
                              void* d_out, int out_size, void* d_ws, size_t ws_size,
                              hipStream_t stream) {
    const float* x    = (const float*)d_in[0];   // 4*256*128*128
    const float* W    = (const float*)d_in[1];   // 2304*256
    const float* bias = (const float*)d_in[2];   // 2304
    float* out = (float*)d_out;

    unsigned char* Wb = (unsigned char*)d_ws;    // 1,179,648 B

    wconv_kernel<<<288, 256, 0, stream>>>(W, Wb);
    dfgemm_kernel<<<1024, 256, 0, stream>>>(Wb, x, bias, out);
}